// Round 12
// baseline (239.088 us; speedup 1.0000x reference)
//
#include <hip/hip_runtime.h>

namespace {

typedef unsigned short u16;
typedef __bf16 bf16x8 __attribute__((ext_vector_type(8)));
typedef __bf16 bf16x2 __attribute__((ext_vector_type(2)));
typedef float f32x4 __attribute__((ext_vector_type(4)));
typedef float f32x16 __attribute__((ext_vector_type(16)));
typedef u16 u16x8v __attribute__((ext_vector_type(8)));
struct alignas(8) u16x4 { u16 x, y, z, w; };
union U32x4 { unsigned int u[4]; bf16x8 v; };

constexpr int kS    = 4096;
constexpr int kE    = 768;
constexpr int kH    = 12;
constexpr int kD    = 64;
constexpr int kQKV  = 2304;   // 3*E
constexpr int kChunk = 256;
constexpr int kC    = 16;     // S / CHUNK
constexpr int kB    = 2;
constexpr float kScale = 0.125f;  // 1/sqrt(64)
constexpr int kRowB = 9216;       // qkv row bytes (2304 fp32)
constexpr int kClsSplit = 16;     // key-chunks per (b,h) for CLS attention

// ---- bf16 helpers (RNE) ---------------------------------------------------
__device__ __forceinline__ u16 f2bf(float f) {
  unsigned int u = __float_as_uint(f);
  u += 0x7FFFu + ((u >> 16) & 1u);
  return (u16)(u >> 16);
}
__device__ __forceinline__ float bf2f(u16 h) {
  return __uint_as_float(((unsigned int)h) << 16);
}
// packed pair via compiler casts -> v_cvt_pk_bf16_f32 (RNE, same as f2bf)
__device__ __forceinline__ unsigned int pkbf(float a, float b) {
  bf16x2 p;
  p[0] = (__bf16)a;
  p[1] = (__bf16)b;
  return __builtin_bit_cast(unsigned int, p);
}

// ---- XCD-aware bijective block swizzle (grid % 8 == 0) ---------------------
__device__ __forceinline__ int xcd_swz(int bid, int nwg) {
  const int cpx = nwg >> 3;
  return (bid & 7) * cpx + (bid >> 3);
}

// ---- async global->LDS, 16B per lane --------------------------------------
__device__ __forceinline__ void glds16(const void* g, void* l) {
  __builtin_amdgcn_global_load_lds(
      (const __attribute__((address_space(1))) unsigned int*)g,
      (__attribute__((address_space(3))) unsigned int*)l, 16, 0, 0);
}

// ---------------------------------------------------------------------------
// Weight pre-pass: W[K][N] fp32 -> Th[N][K] bf16 (transposed, hi only).
// ---------------------------------------------------------------------------
__global__ __launch_bounds__(256)
void wsplit_t(const float* __restrict__ W, u16* __restrict__ Th, int K, int N) {
  __shared__ float tile[64][65];
  const int ntiles = N >> 6;
  const int n0 = (blockIdx.x % ntiles) << 6;
  const int k0 = (blockIdx.x / ntiles) << 6;
  const int t  = threadIdx.x;
  const int r  = t >> 2;
  const int cs = (t & 3) << 4;
  const float* src = W + (size_t)(k0 + r) * N + n0 + cs;
#pragma unroll
  for (int i = 0; i < 4; ++i) {
    float4 v = *(const float4*)(src + 4 * i);
    tile[r][cs + 4 * i + 0] = v.x;
    tile[r][cs + 4 * i + 1] = v.y;
    tile[r][cs + 4 * i + 2] = v.z;
    tile[r][cs + 4 * i + 3] = v.w;
  }
  __syncthreads();
  u16* dh = Th + (size_t)(n0 + r) * K + k0 + cs;
#pragma unroll
  for (int i = 0; i < 4; ++i) {
    u16x4 hq;
    hq.x = f2bf(tile[cs + 4 * i + 0][r]);
    hq.y = f2bf(tile[cs + 4 * i + 1][r]);
    hq.z = f2bf(tile[cs + 4 * i + 2][r]);
    hq.w = f2bf(tile[cs + 4 * i + 3][r]);
    *(u16x4*)(dh + 4 * i) = hq;
  }
}

// ---------------------------------------------------------------------------
// x pre-split: x fp32 [M][K] -> xh, xl bf16 [M][K]. Scratch = d_out.
// ---------------------------------------------------------------------------
__global__ __launch_bounds__(256)
void xsplit(const float* __restrict__ x, u16* __restrict__ xh, u16* __restrict__ xl) {
  const size_t i8 = ((size_t)blockIdx.x * 256 + threadIdx.x) * 8;
  const float4 v0 = *(const float4*)(x + i8);
  const float4 v1 = *(const float4*)(x + i8 + 4);
  const float f[8] = {v0.x, v0.y, v0.z, v0.w, v1.x, v1.y, v1.z, v1.w};
  u16x8v hv, lv;
#pragma unroll
  for (int j = 0; j < 8; ++j) {
    const u16 hb = f2bf(f[j]);
    hv[j] = hb;
    lv[j] = f2bf(f[j] - bf2f(hb));
  }
  *(u16x8v*)(xh + i8) = hv;
  *(u16x8v*)(xl + i8) = lv;
}

// ---------------------------------------------------------------------------
// Split-bf16 MFMA GEMM (round-11, unchanged): depth-2 pipelined, 2-term.
// ---------------------------------------------------------------------------
__global__ __launch_bounds__(256, 2)
void gemm_mfma(const u16* __restrict__ Ahg, const u16* __restrict__ Alg,
               const u16* __restrict__ Bhg,
               const float* __restrict__ bias, float* __restrict__ C,
               int M, int N, int K) {
  __shared__ u16 As_h[2][128][32];
  __shared__ u16 As_l[2][128][32];
  __shared__ u16 Bs_h[2][128][32];

  const int nwg = gridDim.x;
  const int lid = xcd_swz(blockIdx.x, nwg);
  const int nTiles = N >> 7;
  const int m0 = (lid / nTiles) << 7;
  const int n0 = (lid % nTiles) << 7;

  const int tid  = threadIdx.x;
  const int wave = tid >> 6;
  const int lane = tid & 63;
  const int l15  = lane & 15;
  const int khf  = lane >> 4;
  const int wm   = wave >> 1;
  const int wn   = wave & 1;

  const int c0 = wave * 2, c1 = wave * 2 + 1;
  const int rr = lane >> 2;
  const int gg = lane & 3;

  const size_t bOff0 = (size_t)(n0 + c0 * 16 + rr) * K + gg * 8;
  const size_t bOff1 = (size_t)(n0 + c1 * 16 + rr) * K + gg * 8;
  const size_t aOff0 = (size_t)(m0 + c0 * 16 + rr) * K + gg * 8;
  const size_t aOff1 = (size_t)(m0 + c1 * 16 + rr) * K + gg * 8;

  auto STAGE = [&](int p, int k0) {
    glds16(Bhg + bOff0 + k0, &Bs_h[p][c0 * 16][0]);
    glds16(Bhg + bOff1 + k0, &Bs_h[p][c1 * 16][0]);
    glds16(Ahg + aOff0 + k0, &As_h[p][c0 * 16][0]);
    glds16(Ahg + aOff1 + k0, &As_h[p][c1 * 16][0]);
    glds16(Alg + aOff0 + k0, &As_l[p][c0 * 16][0]);
    glds16(Alg + aOff1 + k0, &As_l[p][c1 * 16][0]);
  };

  f32x4 acc[4][4];
#pragma unroll
  for (int i = 0; i < 4; ++i)
#pragma unroll
    for (int j = 0; j < 4; ++j) acc[i][j] = (f32x4){0.f, 0.f, 0.f, 0.f};

  auto COMPUTE = [&](int p) {
    bf16x8 fah[4], fal[4], fbh[4];
#pragma unroll
    for (int f = 0; f < 4; ++f) {
      fah[f] = *(const bf16x8*)&As_h[p][wm * 64 + f * 16 + l15][khf * 8];
      fal[f] = *(const bf16x8*)&As_l[p][wm * 64 + f * 16 + l15][khf * 8];
      fbh[f] = *(const bf16x8*)&Bs_h[p][wn * 64 + f * 16 + l15][khf * 8];
    }
#pragma unroll
    for (int mi = 0; mi < 4; ++mi)
#pragma unroll
      for (int ni = 0; ni < 4; ++ni)
        acc[mi][ni] = __builtin_amdgcn_mfma_f32_16x16x32_bf16(fah[mi], fbh[ni], acc[mi][ni], 0, 0, 0);
#pragma unroll
    for (int mi = 0; mi < 4; ++mi)
#pragma unroll
      for (int ni = 0; ni < 4; ++ni)
        acc[mi][ni] = __builtin_amdgcn_mfma_f32_16x16x32_bf16(fal[mi], fbh[ni], acc[mi][ni], 0, 0, 0);
  };

  STAGE(0, 0);
  STAGE(1, 32);
  int cur = 0;

  for (int k0 = 0; k0 < K - 32; k0 += 32) {
    asm volatile("s_waitcnt vmcnt(6)" ::: "memory");
    __builtin_amdgcn_sched_barrier(0);
    __builtin_amdgcn_s_barrier();

    COMPUTE(cur);

    __builtin_amdgcn_sched_barrier(0);
    asm volatile("s_waitcnt lgkmcnt(0)" ::: "memory");
    __builtin_amdgcn_s_barrier();
    if (k0 + 64 < K) STAGE(cur, k0 + 64);
    cur ^= 1;
  }

  asm volatile("s_waitcnt vmcnt(0)" ::: "memory");
  __builtin_amdgcn_sched_barrier(0);
  __builtin_amdgcn_s_barrier();
  COMPUTE(cur);

#pragma unroll
  for (int ni = 0; ni < 4; ++ni) {
    const int col = n0 + wn * 64 + ni * 16 + l15;
    const float bv = bias[col];
#pragma unroll
    for (int mi = 0; mi < 4; ++mi) {
      const int rbase = m0 + wm * 64 + mi * 16 + khf * 4;
#pragma unroll
      for (int r = 0; r < 4; ++r)
        C[(size_t)(rbase + r) * N + col] = acc[mi][ni][r] + bv;
    }
  }
}

// ---------------------------------------------------------------------------
// Fused RoPE + in-slot bf16 hi/lo pack, coalesced (unchanged).
// ---------------------------------------------------------------------------
__global__ __launch_bounds__(256)
void ropeconv(char* __restrict__ qkvB, const int* __restrict__ coords) {
  const int slot = blockIdx.x * 4 + (threadIdx.x >> 6);   // 0 .. B*S*2-1
  const int lane = threadIdx.x & 63;
  const int sel  = slot & 1;            // 0=q, 1=k
  const int bs   = slot >> 1;           // b*kS + s
  const int s    = bs % kS;

  char* base = qkvB + (size_t)bs * kRowB + sel * 3072;
  const float4* src4 = (const float4*)base;

  float cx = 0.f, cy = 0.f;
  const bool doRope = (s >= 1);
  if (doRope) {
    const int b = bs / kS;
    const int s1 = s - 1;
    cx = (float)coords[((size_t)b * (kS - 1) + s1) * 2 + 0] * (1.0f / 100000.0f);
    cy = (float)coords[((size_t)b * (kS - 1) + s1) * 2 + 1] * (1.0f / 100000.0f);
  }
  const int swz = (sel == 1) ? (s & 7) : 0;
  constexpr float kL2 = 0.83048202372184058696f;  // log2(10000)/16

#pragma unroll
  for (int j = 0; j < 3; ++j) {
    const int fo = lane + 64 * j;       // float4 index in row (0..191)
    float4 v = src4[fo];
    const int o  = fo * 4;              // float offset in row
    const int dp = o & 63;              // within-head d (multiple of 4)
    if (doRope) {
      const float coord = (dp < 32) ? cx : cy;
      const int p0 = dp >> 1;           // pair index (even)
      const float a0 = coord * exp2f(-(float)(p0 & 15) * kL2);
      const float a1 = coord * exp2f(-(float)((p0 + 1) & 15) * kL2);
      const float s0 = __sinf(a0), c0 = __cosf(a0);
      const float s1b = __sinf(a1), c1b = __cosf(a1);
      float4 r;
      r.x = v.x * c0  - v.y * s0;
      r.y = v.y * c0  + v.x * s0;
      r.z = v.z * c1b - v.w * s1b;
      r.w = v.w * c1b + v.z * s1b;
      v = r;
    }
    u16x4 hq, lq;
    hq.x = f2bf(v.x); lq.x = f2bf(v.x - bf2f(hq.x));
    hq.y = f2bf(v.y); lq.y = f2bf(v.y - bf2f(hq.y));
    hq.z = f2bf(v.z); lq.z = f2bf(v.z - bf2f(hq.z));
    hq.w = f2bf(v.w); lq.w = f2bf(v.w - bf2f(hq.w));
    const int h   = o >> 6;             // head
    const int g   = (dp >> 3) ^ swz;    // swizzled 16B group
    const int sub = (dp & 7) * 2;       // byte offset within group (0 or 8)
    char* dst = base + h * 256 + (g << 4) + sub;
    *(u16x4*)dst = hq;
    *(u16x4*)(dst + 128) = lq;
  }
}

// ---------------------------------------------------------------------------
// V pack (unchanged): lower = row-major bf16; upper = V^T swizzled.
// ---------------------------------------------------------------------------
__global__ __launch_bounds__(256)
void vtrans(char* __restrict__ qkvB) {
  __shared__ float tile[64][65];
  const int nsg = kS / 64;
  const int s0  = (blockIdx.x % nsg) * 64;
  const int h   = (blockIdx.x / nsg) % kH;
  const int b   = blockIdx.x / (nsg * kH);
  const int t  = threadIdx.x;
  const int r  = t >> 2;
  const int cs = (t & 3) << 4;
  char* rowp = qkvB + (size_t)(b * kS + s0 + r) * kRowB + 6144 + h * 256;

  float f[16];
#pragma unroll
  for (int i = 0; i < 4; ++i) {
    const float4 v = ((const float4*)(rowp + cs * 4))[i];
    f[4 * i + 0] = v.x; f[4 * i + 1] = v.y; f[4 * i + 2] = v.z; f[4 * i + 3] = v.w;
    tile[r][cs + 4 * i + 0] = v.x;
    tile[r][cs + 4 * i + 1] = v.y;
    tile[r][cs + 4 * i + 2] = v.z;
    tile[r][cs + 4 * i + 3] = v.w;
  }
  __syncthreads();
  {
    u16x8v h0, h1;
#pragma unroll
    for (int j = 0; j < 8; ++j) { h0[j] = f2bf(f[j]); h1[j] = f2bf(f[8 + j]); }
    *(u16x8v*)(rowp + cs * 2)      = h0;
    *(u16x8v*)(rowp + cs * 2 + 16) = h1;
  }
  {
    u16x8v a0, a1;
#pragma unroll
    for (int j = 0; j < 8; ++j) {
      a0[j] = f2bf(tile[cs + j][r]);
      a1[j] = f2bf(tile[cs + 8 + j][r]);
    }
    const int g0 = (cs >> 3) ^ (r & 7);
    const int g1 = ((cs >> 3) + 1) ^ (r & 7);
    *(u16x8v*)(rowp + 128 + (g0 << 4)) = a0;
    *(u16x8v*)(rowp + 128 + (g1 << 4)) = a1;
  }
}

// ---------------------------------------------------------------------------
// Windowed attention v6 — key-split waves for occupancy.
// Grid = B*H*C*4 (1536, %8==0), 128 threads (2 waves). Block owns 64 q-rows;
// the two waves split the window's 32-key tiles (tt = w, w+2, ...), each
// staging its own 12KB LDS tile. No intra-loop barriers (waves independent,
// per-wave vmcnt(0)). End: 3-barrier LDS combine of (O, l) partials; wave 0
// writes the output. V^T staged de-swizzled via per-lane source addressing.
// ---------------------------------------------------------------------------
__global__ __launch_bounds__(128)
void attn_win_mfma(const char* __restrict__ qkvB,
                   u16* __restrict__ oh, u16* __restrict__ ol) {
  __shared__ __align__(16) u16 stage[2][3][2048];  // [wave][KH,KL,VT]; 24 KB
  __shared__ float ls[2][64];

  const int idx  = xcd_swz(blockIdx.x, gridDim.x);
  const int quarter = idx & 3;
  const int c = (idx >> 2) % kC;
  const int h = ((idx >> 2) / kC) % kH;
  const int b = idx / (4 * kC * kH);
  const int tid  = threadIdx.x;
  const int w    = tid >> 6;           // 0..1
  const int lane = tid & 63;
  const int l31  = lane & 31;
  const int h5   = lane >> 5;
  const int hOff = h * 256;
  const int qbase = c * kChunk + quarter * 64;

  u16* KsH = &stage[w][0][0];
  u16* KsL = &stage[w][1][0];
  u16* VsT = &stage[w][2][0];

  // Q fragments (both waves load the same 64 q-rows)
  bf16x8 Qh[2][4], Ql[2][4];
#pragma unroll
  for (int ti = 0; ti < 2; ++ti) {
    const size_t grow = (size_t)(b * kS + qbase + ti * 32 + l31);
#pragma unroll
    for (int ksl = 0; ksl < 4; ++ksl) {
      const char* p = qkvB + grow * kRowB + hOff + ((ksl * 2 + h5) << 4);
      Qh[ti][ksl] = *(const bf16x8*)p;
      Ql[ti][ksl] = *(const bf16x8*)(p + 128);
    }
  }

  f32x16 Oacc[2][2];
#pragma unroll
  for (int a = 0; a < 2; ++a)
#pragma unroll
    for (int d = 0; d < 2; ++d)
#pragma unroll
      for (int i = 0; i < 16; ++i) Oacc[a][d][i] = 0.f;
  float lsA[2] = {0.f, 0.f};

  const int clo = (c > 0) ? c - 1 : 0;
  const int chi = (c < kC - 1) ? c + 1 : kC - 1;
  const int nwin = (chi - clo + 1) * 8;            // 32-key tiles
  const int ntiles = nwin + ((clo != 0) ? 1 : 0);  // + cls tile if needed

  // staging lane decomposition
  const int rowk = lane >> 3;          // K: row within 8-row pass
  const int gk   = lane & 7;           // K: 16B group
  const int dv   = lane >> 2;          // V: d within 16-row pass
  const int gv   = lane & 3;           // V: key group (of 4 in tile)

  U32x4 pa[2][2];

  for (int tt = w; tt < ntiles; tt += 2) {
    const bool isCls = (tt >= nwin);
    const int srow = isCls ? 0 : (clo * kChunk + tt * 32);
    const int s064 = srow & ~63;
    const int halfg = (srow >> 3) & 4;   // group offset of 32-half (0 or 4)

    // ---- stage K hi/lo (32 rows x 128B each) + V^T (64 d x 64B) ----
#pragma unroll
    for (int p = 0; p < 4; ++p) {
      const size_t rbK = (size_t)(b * kS + srow + p * 8 + rowk) * kRowB
                         + 3072 + hOff + (gk << 4);
      glds16(qkvB + rbK,       KsH + p * 512);
      glds16(qkvB + rbK + 128, KsL + p * 512);
      const int d = p * 16 + dv;
      const size_t rbV = (size_t)(b * kS + s064 + d) * kRowB + 6144 + hOff + 128
                         + (((halfg + gv) ^ (d & 7)) << 4);
      glds16(qkvB + rbV, VsT + p * 512);
    }
    asm volatile("s_waitcnt vmcnt(0)" ::: "memory");
    __builtin_amdgcn_sched_barrier(0);

    // ---- S^T = K(32 rows) . Q^T (3-term split) ----
    bf16x8 KH[4], KL[4];
#pragma unroll
    for (int ksl = 0; ksl < 4; ++ksl) {
      const int gg = (((ksl * 2 + h5) ^ (l31 & 7)) << 3);
      KH[ksl] = *(const bf16x8*)&KsH[l31 * 64 + gg];
      KL[ksl] = *(const bf16x8*)&KsL[l31 * 64 + gg];
    }
#pragma unroll
    for (int ti = 0; ti < 2; ++ti) {
      f32x16 S;
#pragma unroll
      for (int i = 0; i < 16; ++i) S[i] = 0.f;
#pragma unroll
      for (int ksl = 0; ksl < 4; ++ksl) {
        S = __builtin_amdgcn_mfma_f32_32x32x16_bf16(KH[ksl], Qh[ti][ksl], S, 0, 0, 0);
        S = __builtin_amdgcn_mfma_f32_32x32x16_bf16(KH[ksl], Ql[ti][ksl], S, 0, 0, 0);
        S = __builtin_amdgcn_mfma_f32_32x32x16_bf16(KL[ksl], Qh[ti][ksl], S, 0, 0, 0);
      }
      unsigned int wpk[4][2], sw[4][2];
      float lacc = 0.f;
#pragma unroll
      for (int m = 0; m < 4; ++m) {
        float e[4];
#pragma unroll
        for (int r = 0; r < 4; ++r) {
          float ev = __expf(S[4 * m + r] * kScale);
          if (isCls && !(m == 0 && r == 0 && h5 == 0)) ev = 0.f;
          e[r] = ev;
        }
        lacc += (e[0] + e[1]) + (e[2] + e[3]);
        wpk[m][0] = pkbf(e[0], e[1]);
        wpk[m][1] = pkbf(e[2], e[3]);
      }
      lsA[ti] += lacc;
#pragma unroll
      for (int m = 0; m < 4; ++m) {
        sw[m][0] = __shfl_xor(wpk[m][0], 32);
        sw[m][1] = __shfl_xor(wpk[m][1], 32);
      }
#pragma unroll
      for (int jj = 0; jj < 2; ++jj) {
        const int m0 = 2 * jj, m1 = 2 * jj + 1;
        U32x4& P = pa[ti][jj];
        P.u[0] = h5 ? sw[m1][0]  : wpk[m0][0];
        P.u[1] = h5 ? sw[m1][1]  : wpk[m0][1];
        P.u[2] = h5 ? wpk[m1][0] : sw[m0][0];
        P.u[3] = h5 ? wpk[m1][1] : sw[m0][1];
      }
    }

    // ---- O += P @ V (32 keys) ----
#pragma unroll
    for (int sl = 0; sl < 2; ++sl) {
#pragma unroll
      for (int dt = 0; dt < 2; ++dt) {
        const int vrow = dt * 32 + l31;
        const bf16x8 vb = *(const bf16x8*)&VsT[vrow * 32 + ((sl * 2 + h5) << 3)];
        Oacc[0][dt] = __builtin_amdgcn_mfma_f32_32x32x16_bf16(pa[0][sl].v, vb, Oacc[0][dt], 0, 0, 0);
        Oacc[1][dt] = __builtin_amdgcn_mfma_f32_32x32x16_bf16(pa[1][sl].v, vb, Oacc[1][dt], 0, 0, 0);
      }
    }
  }

  // ---- combine across the two waves ----
  __syncthreads();                                    // all staging reads done
  float* comb = (float*)&stage[0][0][0];              // 64q x 64d fp32 (16 KB)

  if (w == 1) {
#pragma unroll
    for (int ti = 0; ti < 2; ++ti) {
#pragma unroll
      for (int m = 0; m < 4; ++m)
#pragma unroll
        for (int r = 0; r < 4; ++r) {
          const int q = ti * 32 + r + 8 * m + 4 * h5;
#pragma unroll
          for (int dt = 0; dt < 2; ++dt)
            comb[q * 64 + dt * 32 + l31] = Oacc[ti][dt][4 * m + r];
        }
      float v = lsA[ti];
      v += __shfl_xor(v, 32);
      ls[1][ti * 32 + l31] = v;
    }
  }
  __syncthreads();
  if (w == 0) {
#pragma unroll
    for (int ti = 0; ti < 2; ++ti) {
#pragma unroll
      for (int m = 0; m < 4; ++m)
#pragma unroll
        for (int r = 0; r < 4; ++r) {
          const int q = ti * 32 + r + 8 * m + 4 * h5;
#pragma unroll
          for (int dt = 0; dt < 2; ++dt)
            Oacc[ti][dt][4 * m + r] += comb[q * 64 + dt * 32 + l31];
        }
      float v = lsA[ti];
      v += __shfl_xor(v, 32);
      ls[0][ti * 32 + l31] = v + ls[1][ti * 32 + l31];
    }
  }
  __syncthreads();
  if (w == 0) {
#pragma unroll
    for (int ti = 0; ti < 2; ++ti)
#pragma unroll
      for (int m = 0; m < 4; ++m)
#pragma unroll
        for (int r = 0; r < 4; ++r) {
          const int qr = r + 8 * m + 4 * h5;
          const float inv = 1.0f / ls[0][ti * 32 + qr];
          const size_t grow = (size_t)(b * kS + qbase + ti * 32 + qr);
#pragma unroll
          for (int dt = 0; dt < 2; ++dt) {
            const float val = Oacc[ti][dt][4 * m + r] * inv;
            const u16 hb = f2bf(val);
            const size_t o = grow * (size_t)kE + h * 64 + dt * 32 + l31;
            oh[o] = hb;
            ol[o] = f2bf(val - bf2f(hb));
          }
        }
  }
}

// ---------------------------------------------------------------------------
// CLS attention, pass 1: partials over 256-key chunks (16-way split).
// ---------------------------------------------------------------------------
__global__ __launch_bounds__(64)
void attn_cls_part(const char* __restrict__ qkvB, float* __restrict__ part) {
  __shared__ float obuf[64][64];
  const int p = blockIdx.x & (kClsSplit - 1);
  const int h = (blockIdx.x / kClsSplit) % kH;
  const int b = blockIdx.x / (kClsSplit * kH);
  const int lane = threadIdx.x;
  const int hOff = h * 256;
  const int keysPer = kS / kClsSplit;   // 256

  float q[64];
  {
    const char* qp = qkvB + (size_t)(b * kS) * kRowB + hOff;
#pragma unroll
    for (int g = 0; g < 8; ++g) {
      const u16x8v hv = *(const u16x8v*)(qp + (g << 4));
      const u16x8v lv = *(const u16x8v*)(qp + 128 + (g << 4));
#pragma unroll
      for (int j = 0; j < 8; ++j) q[g * 8 + j] = bf2f(hv[j]) + bf2f(lv[j]);
    }
  }

  float oacc[64] = {};
  float l = 0.f;

  for (int i = 0; i < keysPer / 64; ++i) {
    const int sk = p * keysPer + i * 64 + lane;
    const char* rp = qkvB + (size_t)(b * kS + sk) * kRowB;
    const int swz = sk & 7;
    float dp = 0.f;
#pragma unroll
    for (int g = 0; g < 8; ++g) {
      const char* kp = rp + 3072 + hOff + ((g ^ swz) << 4);
      const u16x8v kh = *(const u16x8v*)kp;
      const u16x8v kl = *(const u16x8v*)(kp + 128);
#pragma unroll
      for (int j = 0; j < 8; ++j)
        dp = fmaf(q[g * 8 + j], bf2f(kh[j]) + bf2f(kl[j]), dp);
    }
    const float e = __expf(dp * kScale);
    l += e;
    const char* vp = rp + 6144 + hOff;
#pragma unroll
    for (int g = 0; g < 8; ++g) {
      const u16x8v vv = *(const u16x8v*)(vp + (g << 4));
#pragma unroll
      for (int j = 0; j < 8; ++j)
        oacc[g * 8 + j] = fmaf(e, bf2f(vv[j]), oacc[g * 8 + j]);
    }
  }

  float L = l;
#pragma unroll
  for (int off = 32; off > 0; off >>= 1) L += __shfl_xor(L, off);

#pragma unroll
  for (int d = 0; d < 64; ++d) obuf[lane][d] = oacc[d];
  __syncthreads();

  float sum = 0.f;
  for (int ln = 0; ln < 64; ++ln) sum += obuf[ln][lane];

  float* dst = part + (size_t)blockIdx.x * 66;
  dst[lane] = sum;
  if (lane == 0) dst[64] = L;
}

// ---------------------------------------------------------------------------
// CLS attention, pass 2: combine partials, normalize, write oh/ol row 0.
// ---------------------------------------------------------------------------
__global__ __launch_bounds__(64)
void attn_cls_comb(const float* __restrict__ part,
                   u16* __restrict__ oh, u16* __restrict__ ol) {
  const int h = blockIdx.x % kH;
  const int b = blockIdx.x / kH;
  const int lane = threadIdx.x;
  const float* src = part + (size_t)((b * kH + h) * kClsSplit) * 66;
  float s = 0.f, L = 0.f;
#pragma unroll
  for (int p = 0; p < kClsSplit; ++p) {
    s += src[p * 66 + lane];
    L += src[p * 66 + 64];
  }
  const float v = s / L;
  const u16 hb = f2bf(v);
  const size_t off0 = (size_t)(b * kS) * kE + h * kD + lane;
  oh[off0] = hb;
  ol[off0] = f2bf(v - bf2f(hb));
}

}  // namespace

// ---------------------------------------------------------------------------
extern "C" void kernel_launch(void* const* d_in, const int* in_sizes, int n_in,
                              void* d_out, int out_size, void* d_ws, size_t ws_size,
                              hipStream_t stream) {
  const float* x      = (const float*)d_in[0];
  const int*   coords = (const int*)d_in[1];
  const float* Wqkv   = (const float*)d_in[2];
  const float* bqkv   = (const float*)d_in[3];
  const float* Wout   = (const float*)d_in[4];
  const float* bout   = (const float*)d_in[5];
  float* out = (float*)d_out;

  // Workspace (100,663,296 B):
  //   A [0 .. 75,497,472)  qkv fp32 -> packed in-slot (q,k hi/lo; v bf16 + V^T)
  //       (aliased post-cls: WoTh @0)
  //   B [75,497,472 .. +25,165,824)  phase1: WqTh @0 (3.5 MB)
  //                                  phase2: oh @0, ol @+12,582,912
  // d_out doubles as scratch (stream-ordered): xh/xl, then cls partials,
  // then the final output overwrites it.
  char* wsb = (char*)d_ws;
  float* qkv  = (float*)wsb;
  char*  qkvB = wsb;
  u16* WoTh = (u16*)wsb;
  char* rb = wsb + 75497472;
  u16* WqTh = (u16*)rb;
  u16* oh   = (u16*)rb;
  u16* ol   = (u16*)(rb + 12582912);
  u16* xh   = (u16*)d_out;
  u16* xl   = (u16*)((char*)d_out + 12582912);
  float* clsPart = out;

  const int M = kB * kS;  // 8192

  // 1. Transpose+bf16 W_qkv (hi only)
  wsplit_t<<<(kQKV / 64) * (kE / 64), 256, 0, stream>>>(Wqkv, WqTh, kE, kQKV);

  // 2. x pre-split (scratch in d_out) + QKV projection (pipelined 2-term GEMM)
  {
    xsplit<<<(M * kE) / (256 * 8), 256, 0, stream>>>(x, xh, xl);
    const int nwg = (kQKV / 128) * (M / 128);   // 1152, %8==0
    gemm_mfma<<<nwg, 256, 0, stream>>>(xh, xl, WqTh, bqkv, qkv, M, kQKV, kE);
  }

  // 3. RoPE + q/k in-slot bf16 pack (coalesced, wave-per-row)
  {
    const int slots = kB * kS * 2;              // 16384
    ropeconv<<<slots / 4, 256, 0, stream>>>(qkvB, coords);
  }

  // 4. V pack
  vtrans<<<kB * kH * (kS / 64), 256, 0, stream>>>(qkvB);

  // 5. Windowed attention (key-split waves, XCD-swizzled) -> oh/ol
  attn_win_mfma<<<kB * kH * kC * 4, 128, 0, stream>>>(qkvB, oh, ol);

  // 6. CLS attention: 16-way split partials (scratch in d_out) + combine
  attn_cls_part<<<kB * kH * kClsSplit, 64, 0, stream>>>(qkvB, clsPart);
  attn_cls_comb<<<kB * kH, 64, 0, stream>>>(clsPart, oh, ol);

  // 7. Transpose+bf16 W_out (into dead qkv space)
  wsplit_t<<<(kE / 64) * (kE / 64), 256, 0, stream>>>(Wout, WoTh, kE, kE);

  // 8. Output projection (pipelined 2-term, XCD-swizzled)
  {
    const int nwg = (kE / 128) * (M / 128);     // 384, %8==0
    gemm_mfma<<<nwg, 256, 0, stream>>>(oh, ol, WoTh, bout, out, M, kE, kE);
  }
}

// Round 13
// 234.045 us; speedup vs baseline: 1.0215x; 1.0215x over previous
//
#include <hip/hip_runtime.h>

namespace {

typedef unsigned short u16;
typedef __bf16 bf16x8 __attribute__((ext_vector_type(8)));
typedef __bf16 bf16x2 __attribute__((ext_vector_type(2)));
typedef float f32x4 __attribute__((ext_vector_type(4)));
typedef float f32x16 __attribute__((ext_vector_type(16)));
typedef u16 u16x8v __attribute__((ext_vector_type(8)));
struct alignas(8) u16x4 { u16 x, y, z, w; };
union U32x4 { unsigned int u[4]; bf16x8 v; };

constexpr int kS    = 4096;
constexpr int kE    = 768;
constexpr int kH    = 12;
constexpr int kD    = 64;
constexpr int kQKV  = 2304;   // 3*E
constexpr int kChunk = 256;
constexpr int kC    = 16;     // S / CHUNK
constexpr int kB    = 2;
constexpr float kScale = 0.125f;  // 1/sqrt(64)
constexpr int kRowB = 9216;       // qkv row bytes (2304 fp32)
constexpr int kClsSplit = 16;     // key-chunks per (b,h) for CLS attention

// ---- bf16 helpers (RNE) ---------------------------------------------------
__device__ __forceinline__ u16 f2bf(float f) {
  unsigned int u = __float_as_uint(f);
  u += 0x7FFFu + ((u >> 16) & 1u);
  return (u16)(u >> 16);
}
__device__ __forceinline__ float bf2f(u16 h) {
  return __uint_as_float(((unsigned int)h) << 16);
}
// packed pair via compiler casts -> v_cvt_pk_bf16_f32 (RNE, same as f2bf)
__device__ __forceinline__ unsigned int pkbf(float a, float b) {
  bf16x2 p;
  p[0] = (__bf16)a;
  p[1] = (__bf16)b;
  return __builtin_bit_cast(unsigned int, p);
}

// ---- XCD-aware bijective block swizzle (grid % 8 == 0) ---------------------
__device__ __forceinline__ int xcd_swz(int bid, int nwg) {
  const int cpx = nwg >> 3;
  return (bid & 7) * cpx + (bid >> 3);
}

// ---- async global->LDS, 16B per lane --------------------------------------
__device__ __forceinline__ void glds16(const void* g, void* l) {
  __builtin_amdgcn_global_load_lds(
      (const __attribute__((address_space(1))) unsigned int*)g,
      (__attribute__((address_space(3))) unsigned int*)l, 16, 0, 0);
}

// ---------------------------------------------------------------------------
// Weight pre-pass: W[K][N] fp32 -> Th[N][K] bf16 (transposed, hi only).
// ---------------------------------------------------------------------------
__global__ __launch_bounds__(256)
void wsplit_t(const float* __restrict__ W, u16* __restrict__ Th, int K, int N) {
  __shared__ float tile[64][65];
  const int ntiles = N >> 6;
  const int n0 = (blockIdx.x % ntiles) << 6;
  const int k0 = (blockIdx.x / ntiles) << 6;
  const int t  = threadIdx.x;
  const int r  = t >> 2;
  const int cs = (t & 3) << 4;
  const float* src = W + (size_t)(k0 + r) * N + n0 + cs;
#pragma unroll
  for (int i = 0; i < 4; ++i) {
    float4 v = *(const float4*)(src + 4 * i);
    tile[r][cs + 4 * i + 0] = v.x;
    tile[r][cs + 4 * i + 1] = v.y;
    tile[r][cs + 4 * i + 2] = v.z;
    tile[r][cs + 4 * i + 3] = v.w;
  }
  __syncthreads();
  u16* dh = Th + (size_t)(n0 + r) * K + k0 + cs;
#pragma unroll
  for (int i = 0; i < 4; ++i) {
    u16x4 hq;
    hq.x = f2bf(tile[cs + 4 * i + 0][r]);
    hq.y = f2bf(tile[cs + 4 * i + 1][r]);
    hq.z = f2bf(tile[cs + 4 * i + 2][r]);
    hq.w = f2bf(tile[cs + 4 * i + 3][r]);
    *(u16x4*)(dh + 4 * i) = hq;
  }
}

// ---------------------------------------------------------------------------
// x pre-split: x fp32 [M][K] -> xh, xl bf16 [M][K]. Scratch = d_out.
// ---------------------------------------------------------------------------
__global__ __launch_bounds__(256)
void xsplit(const float* __restrict__ x, u16* __restrict__ xh, u16* __restrict__ xl) {
  const size_t i8 = ((size_t)blockIdx.x * 256 + threadIdx.x) * 8;
  const float4 v0 = *(const float4*)(x + i8);
  const float4 v1 = *(const float4*)(x + i8 + 4);
  const float f[8] = {v0.x, v0.y, v0.z, v0.w, v1.x, v1.y, v1.z, v1.w};
  u16x8v hv, lv;
#pragma unroll
  for (int j = 0; j < 8; ++j) {
    const u16 hb = f2bf(f[j]);
    hv[j] = hb;
    lv[j] = f2bf(f[j] - bf2f(hb));
  }
  *(u16x8v*)(xh + i8) = hv;
  *(u16x8v*)(xl + i8) = lv;
}

// ---------------------------------------------------------------------------
// Split-bf16 MFMA GEMM (round-11, unchanged): depth-2 pipelined, 2-term.
// ---------------------------------------------------------------------------
__global__ __launch_bounds__(256, 2)
void gemm_mfma(const u16* __restrict__ Ahg, const u16* __restrict__ Alg,
               const u16* __restrict__ Bhg,
               const float* __restrict__ bias, float* __restrict__ C,
               int M, int N, int K) {
  __shared__ u16 As_h[2][128][32];
  __shared__ u16 As_l[2][128][32];
  __shared__ u16 Bs_h[2][128][32];

  const int nwg = gridDim.x;
  const int lid = xcd_swz(blockIdx.x, nwg);
  const int nTiles = N >> 7;
  const int m0 = (lid / nTiles) << 7;
  const int n0 = (lid % nTiles) << 7;

  const int tid  = threadIdx.x;
  const int wave = tid >> 6;
  const int lane = tid & 63;
  const int l15  = lane & 15;
  const int khf  = lane >> 4;
  const int wm   = wave >> 1;
  const int wn   = wave & 1;

  const int c0 = wave * 2, c1 = wave * 2 + 1;
  const int rr = lane >> 2;
  const int gg = lane & 3;

  const size_t bOff0 = (size_t)(n0 + c0 * 16 + rr) * K + gg * 8;
  const size_t bOff1 = (size_t)(n0 + c1 * 16 + rr) * K + gg * 8;
  const size_t aOff0 = (size_t)(m0 + c0 * 16 + rr) * K + gg * 8;
  const size_t aOff1 = (size_t)(m0 + c1 * 16 + rr) * K + gg * 8;

  auto STAGE = [&](int p, int k0) {
    glds16(Bhg + bOff0 + k0, &Bs_h[p][c0 * 16][0]);
    glds16(Bhg + bOff1 + k0, &Bs_h[p][c1 * 16][0]);
    glds16(Ahg + aOff0 + k0, &As_h[p][c0 * 16][0]);
    glds16(Ahg + aOff1 + k0, &As_h[p][c1 * 16][0]);
    glds16(Alg + aOff0 + k0, &As_l[p][c0 * 16][0]);
    glds16(Alg + aOff1 + k0, &As_l[p][c1 * 16][0]);
  };

  f32x4 acc[4][4];
#pragma unroll
  for (int i = 0; i < 4; ++i)
#pragma unroll
    for (int j = 0; j < 4; ++j) acc[i][j] = (f32x4){0.f, 0.f, 0.f, 0.f};

  auto COMPUTE = [&](int p) {
    bf16x8 fah[4], fal[4], fbh[4];
#pragma unroll
    for (int f = 0; f < 4; ++f) {
      fah[f] = *(const bf16x8*)&As_h[p][wm * 64 + f * 16 + l15][khf * 8];
      fal[f] = *(const bf16x8*)&As_l[p][wm * 64 + f * 16 + l15][khf * 8];
      fbh[f] = *(const bf16x8*)&Bs_h[p][wn * 64 + f * 16 + l15][khf * 8];
    }
#pragma unroll
    for (int mi = 0; mi < 4; ++mi)
#pragma unroll
      for (int ni = 0; ni < 4; ++ni)
        acc[mi][ni] = __builtin_amdgcn_mfma_f32_16x16x32_bf16(fah[mi], fbh[ni], acc[mi][ni], 0, 0, 0);
#pragma unroll
    for (int mi = 0; mi < 4; ++mi)
#pragma unroll
      for (int ni = 0; ni < 4; ++ni)
        acc[mi][ni] = __builtin_amdgcn_mfma_f32_16x16x32_bf16(fal[mi], fbh[ni], acc[mi][ni], 0, 0, 0);
  };

  STAGE(0, 0);
  STAGE(1, 32);
  int cur = 0;

  for (int k0 = 0; k0 < K - 32; k0 += 32) {
    asm volatile("s_waitcnt vmcnt(6)" ::: "memory");
    __builtin_amdgcn_sched_barrier(0);
    __builtin_amdgcn_s_barrier();

    COMPUTE(cur);

    __builtin_amdgcn_sched_barrier(0);
    asm volatile("s_waitcnt lgkmcnt(0)" ::: "memory");
    __builtin_amdgcn_s_barrier();
    if (k0 + 64 < K) STAGE(cur, k0 + 64);
    cur ^= 1;
  }

  asm volatile("s_waitcnt vmcnt(0)" ::: "memory");
  __builtin_amdgcn_sched_barrier(0);
  __builtin_amdgcn_s_barrier();
  COMPUTE(cur);

#pragma unroll
  for (int ni = 0; ni < 4; ++ni) {
    const int col = n0 + wn * 64 + ni * 16 + l15;
    const float bv = bias[col];
#pragma unroll
    for (int mi = 0; mi < 4; ++mi) {
      const int rbase = m0 + wm * 64 + mi * 16 + khf * 4;
#pragma unroll
      for (int r = 0; r < 4; ++r)
        C[(size_t)(rbase + r) * N + col] = acc[mi][ni][r] + bv;
    }
  }
}

// ---------------------------------------------------------------------------
// Fused RoPE + in-slot bf16 hi/lo pack, coalesced (unchanged).
// ---------------------------------------------------------------------------
__global__ __launch_bounds__(256)
void ropeconv(char* __restrict__ qkvB, const int* __restrict__ coords) {
  const int slot = blockIdx.x * 4 + (threadIdx.x >> 6);   // 0 .. B*S*2-1
  const int lane = threadIdx.x & 63;
  const int sel  = slot & 1;            // 0=q, 1=k
  const int bs   = slot >> 1;           // b*kS + s
  const int s    = bs % kS;

  char* base = qkvB + (size_t)bs * kRowB + sel * 3072;
  const float4* src4 = (const float4*)base;

  float cx = 0.f, cy = 0.f;
  const bool doRope = (s >= 1);
  if (doRope) {
    const int b = bs / kS;
    const int s1 = s - 1;
    cx = (float)coords[((size_t)b * (kS - 1) + s1) * 2 + 0] * (1.0f / 100000.0f);
    cy = (float)coords[((size_t)b * (kS - 1) + s1) * 2 + 1] * (1.0f / 100000.0f);
  }
  const int swz = (sel == 1) ? (s & 7) : 0;
  constexpr float kL2 = 0.83048202372184058696f;  // log2(10000)/16

#pragma unroll
  for (int j = 0; j < 3; ++j) {
    const int fo = lane + 64 * j;       // float4 index in row (0..191)
    float4 v = src4[fo];
    const int o  = fo * 4;              // float offset in row
    const int dp = o & 63;              // within-head d (multiple of 4)
    if (doRope) {
      const float coord = (dp < 32) ? cx : cy;
      const int p0 = dp >> 1;           // pair index (even)
      const float a0 = coord * exp2f(-(float)(p0 & 15) * kL2);
      const float a1 = coord * exp2f(-(float)((p0 + 1) & 15) * kL2);
      const float s0 = __sinf(a0), c0 = __cosf(a0);
      const float s1b = __sinf(a1), c1b = __cosf(a1);
      float4 r;
      r.x = v.x * c0  - v.y * s0;
      r.y = v.y * c0  + v.x * s0;
      r.z = v.z * c1b - v.w * s1b;
      r.w = v.w * c1b + v.z * s1b;
      v = r;
    }
    u16x4 hq, lq;
    hq.x = f2bf(v.x); lq.x = f2bf(v.x - bf2f(hq.x));
    hq.y = f2bf(v.y); lq.y = f2bf(v.y - bf2f(hq.y));
    hq.z = f2bf(v.z); lq.z = f2bf(v.z - bf2f(hq.z));
    hq.w = f2bf(v.w); lq.w = f2bf(v.w - bf2f(hq.w));
    const int h   = o >> 6;             // head
    const int g   = (dp >> 3) ^ swz;    // swizzled 16B group
    const int sub = (dp & 7) * 2;       // byte offset within group (0 or 8)
    char* dst = base + h * 256 + (g << 4) + sub;
    *(u16x4*)dst = hq;
    *(u16x4*)(dst + 128) = lq;
  }
}

// ---------------------------------------------------------------------------
// V pack (unchanged): lower = row-major bf16; upper = V^T swizzled.
// ---------------------------------------------------------------------------
__global__ __launch_bounds__(256)
void vtrans(char* __restrict__ qkvB) {
  __shared__ float tile[64][65];
  const int nsg = kS / 64;
  const int s0  = (blockIdx.x % nsg) * 64;
  const int h   = (blockIdx.x / nsg) % kH;
  const int b   = blockIdx.x / (nsg * kH);
  const int t  = threadIdx.x;
  const int r  = t >> 2;
  const int cs = (t & 3) << 4;
  char* rowp = qkvB + (size_t)(b * kS + s0 + r) * kRowB + 6144 + h * 256;

  float f[16];
#pragma unroll
  for (int i = 0; i < 4; ++i) {
    const float4 v = ((const float4*)(rowp + cs * 4))[i];
    f[4 * i + 0] = v.x; f[4 * i + 1] = v.y; f[4 * i + 2] = v.z; f[4 * i + 3] = v.w;
    tile[r][cs + 4 * i + 0] = v.x;
    tile[r][cs + 4 * i + 1] = v.y;
    tile[r][cs + 4 * i + 2] = v.z;
    tile[r][cs + 4 * i + 3] = v.w;
  }
  __syncthreads();
  {
    u16x8v h0, h1;
#pragma unroll
    for (int j = 0; j < 8; ++j) { h0[j] = f2bf(f[j]); h1[j] = f2bf(f[8 + j]); }
    *(u16x8v*)(rowp + cs * 2)      = h0;
    *(u16x8v*)(rowp + cs * 2 + 16) = h1;
  }
  {
    u16x8v a0, a1;
#pragma unroll
    for (int j = 0; j < 8; ++j) {
      a0[j] = f2bf(tile[cs + j][r]);
      a1[j] = f2bf(tile[cs + 8 + j][r]);
    }
    const int g0 = (cs >> 3) ^ (r & 7);
    const int g1 = ((cs >> 3) + 1) ^ (r & 7);
    *(u16x8v*)(rowp + 128 + (g0 << 4)) = a0;
    *(u16x8v*)(rowp + 128 + (g1 << 4)) = a1;
  }
}

// ---------------------------------------------------------------------------
// Windowed attention v7 — round-11 structure + depth-2 staging pipeline.
// Grid = kB*kH*kC*2 (768), 128 threads (2 waves); each wave owns 64 q-rows,
// both process all 64-key tiles. Double-buffered K/V LDS; counted vmcnt(12)
// keeps the next tile's 12 glds/wave in flight across both barriers.
// ---------------------------------------------------------------------------
__global__ __launch_bounds__(128)
void attn_win_mfma(const char* __restrict__ qkvB,
                   u16* __restrict__ oh, u16* __restrict__ ol) {
  __shared__ __align__(16) u16 KsH[2][4096];
  __shared__ __align__(16) u16 KsL[2][4096];
  __shared__ __align__(16) u16 VsT[2][4096];
  __shared__ float ls[2][64];

  const int idx  = xcd_swz(blockIdx.x, gridDim.x);
  const int half = idx & 1;
  const int c = (idx >> 1) % kC;
  const int h = ((idx >> 1) / kC) % kH;
  const int b = idx / (2 * kC * kH);
  const int tid  = threadIdx.x;
  const int w    = tid >> 6;           // 0..1
  const int lane = tid & 63;
  const int l31  = lane & 31;
  const int h5   = lane >> 5;
  const int hOff = h * 256;
  const int qbase = c * kChunk + half * 128 + w * 64;

  bf16x8 Qh[2][4], Ql[2][4];
#pragma unroll
  for (int ti = 0; ti < 2; ++ti) {
    const size_t grow = (size_t)(b * kS + qbase + ti * 32 + l31);
#pragma unroll
    for (int ksl = 0; ksl < 4; ++ksl) {
      const char* p = qkvB + grow * kRowB + hOff + ((ksl * 2 + h5) << 4);
      Qh[ti][ksl] = *(const bf16x8*)p;
      Ql[ti][ksl] = *(const bf16x8*)(p + 128);
    }
  }

  f32x16 Oacc[2][2];
#pragma unroll
  for (int a = 0; a < 2; ++a)
#pragma unroll
    for (int d = 0; d < 2; ++d)
#pragma unroll
      for (int i = 0; i < 16; ++i) Oacc[a][d][i] = 0.f;
  float lsA[2] = {0.f, 0.f};

  const int clo = (c > 0) ? c - 1 : 0;
  const int chi = (c < kC - 1) ? c + 1 : kC - 1;
  const int nwin = (chi - clo + 1) * 4;            // 64-key tiles
  const int ntiles = nwin + ((clo != 0) ? 1 : 0);

  U32x4 pa[2][4];

  // stage a 64-key tile into buffer p (12 glds per wave; waves split rows)
  auto STAGE = [&](int p, int tt) {
    const int srow = (tt >= nwin) ? 0 : (clo * kChunk + tt * 64);
#pragma unroll
    for (int j = 0; j < 4; ++j) {
      const int cb = w * 256 + j * 64;     // wave-uniform LDS chunk base
      const int ch = cb + lane;
      const size_t gr = (size_t)(b * kS + srow + (ch >> 3)) * kRowB + ((ch & 7) << 4);
      glds16(qkvB + gr + 3072 + hOff,       &KsH[p][cb * 8]);
      glds16(qkvB + gr + 3072 + hOff + 128, &KsL[p][cb * 8]);
      glds16(qkvB + gr + 6144 + hOff + 128, &VsT[p][cb * 8]);
    }
  };

  auto COMPUTE = [&](int p, int tt) {
    const bool isCls = (tt >= nwin);
#pragma unroll
    for (int kt = 0; kt < 2; ++kt) {
      bf16x8 KH[4], KL[4];
      const int krow = kt * 32 + l31;
#pragma unroll
      for (int ksl = 0; ksl < 4; ++ksl) {
        const int gg = (((ksl * 2 + h5) ^ (krow & 7)) << 3);
        KH[ksl] = *(const bf16x8*)&KsH[p][krow * 64 + gg];
        KL[ksl] = *(const bf16x8*)&KsL[p][krow * 64 + gg];
      }
#pragma unroll
      for (int ti = 0; ti < 2; ++ti) {
        f32x16 S;
#pragma unroll
        for (int i = 0; i < 16; ++i) S[i] = 0.f;
#pragma unroll
        for (int ksl = 0; ksl < 4; ++ksl) {
          S = __builtin_amdgcn_mfma_f32_32x32x16_bf16(KH[ksl], Qh[ti][ksl], S, 0, 0, 0);
          S = __builtin_amdgcn_mfma_f32_32x32x16_bf16(KH[ksl], Ql[ti][ksl], S, 0, 0, 0);
          S = __builtin_amdgcn_mfma_f32_32x32x16_bf16(KL[ksl], Qh[ti][ksl], S, 0, 0, 0);
        }
        unsigned int wpk[4][2], sw[4][2];
        float lacc = 0.f;
#pragma unroll
        for (int m = 0; m < 4; ++m) {
          float e[4];
#pragma unroll
          for (int r = 0; r < 4; ++r) {
            float ev = __expf(S[4 * m + r] * kScale);
            if (isCls && !(kt == 0 && m == 0 && r == 0 && h5 == 0)) ev = 0.f;
            e[r] = ev;
          }
          lacc += (e[0] + e[1]) + (e[2] + e[3]);
          wpk[m][0] = pkbf(e[0], e[1]);
          wpk[m][1] = pkbf(e[2], e[3]);
        }
        lsA[ti] += lacc;
#pragma unroll
        for (int m = 0; m < 4; ++m) {
          sw[m][0] = __shfl_xor(wpk[m][0], 32);
          sw[m][1] = __shfl_xor(wpk[m][1], 32);
        }
#pragma unroll
        for (int jj = 0; jj < 2; ++jj) {
          const int m0 = 2 * jj, m1 = 2 * jj + 1;
          U32x4& P = pa[ti][kt * 2 + jj];
          P.u[0] = h5 ? sw[m1][0]  : wpk[m0][0];
          P.u[1] = h5 ? sw[m1][1]  : wpk[m0][1];
          P.u[2] = h5 ? wpk[m1][0] : sw[m0][0];
          P.u[3] = h5 ? wpk[m1][1] : sw[m0][1];
        }
      }
    }
#pragma unroll
    for (int sl = 0; sl < 4; ++sl) {
#pragma unroll
      for (int dt = 0; dt < 2; ++dt) {
        const int vrow = dt * 32 + l31;
        const bf16x8 vb =
            *(const bf16x8*)&VsT[p][vrow * 64 + ((((sl * 2 + h5) ^ (vrow & 7))) << 3)];
        Oacc[0][dt] = __builtin_amdgcn_mfma_f32_32x32x16_bf16(pa[0][sl].v, vb, Oacc[0][dt], 0, 0, 0);
        Oacc[1][dt] = __builtin_amdgcn_mfma_f32_32x32x16_bf16(pa[1][sl].v, vb, Oacc[1][dt], 0, 0, 0);
      }
    }
  };

  // prologue: two tiles in flight (12 glds/wave each)
  STAGE(0, 0);
  if (ntiles > 1) STAGE(1, 1);
  int cur = 0;

  for (int tt = 0; tt < ntiles; ++tt) {
    if (tt + 1 < ntiles) {
      asm volatile("s_waitcnt vmcnt(12)" ::: "memory");  // buf[cur] landed
    } else {
      asm volatile("s_waitcnt vmcnt(0)" ::: "memory");   // last tile: drain
    }
    __builtin_amdgcn_sched_barrier(0);
    __builtin_amdgcn_s_barrier();

    COMPUTE(cur, tt);

    __builtin_amdgcn_sched_barrier(0);
    asm volatile("s_waitcnt lgkmcnt(0)" ::: "memory");   // buf[cur] reads done
    __builtin_amdgcn_s_barrier();
    if (tt + 2 < ntiles) STAGE(cur, tt + 2);             // refill freed buffer
    cur ^= 1;
  }

  // denominator exchange (per-wave LDS)
#pragma unroll
  for (int ti = 0; ti < 2; ++ti) {
    float v = lsA[ti];
    v += __shfl_xor(v, 32);
    ls[w][ti * 32 + l31] = v;
  }

#pragma unroll
  for (int ti = 0; ti < 2; ++ti)
#pragma unroll
    for (int m = 0; m < 4; ++m)
#pragma unroll
      for (int r = 0; r < 4; ++r) {
        const int qr = r + 8 * m + 4 * h5;
        const float inv = 1.0f / ls[w][ti * 32 + qr];
        const size_t grow = (size_t)(b * kS + qbase + ti * 32 + qr);
#pragma unroll
        for (int dt = 0; dt < 2; ++dt) {
          const float val = Oacc[ti][dt][4 * m + r] * inv;
          const u16 hb = f2bf(val);
          const size_t o = grow * (size_t)kE + h * 64 + dt * 32 + l31;
          oh[o] = hb;
          ol[o] = f2bf(val - bf2f(hb));
        }
      }
}

// ---------------------------------------------------------------------------
// CLS attention, pass 1: partials over 256-key chunks (16-way split).
// ---------------------------------------------------------------------------
__global__ __launch_bounds__(64)
void attn_cls_part(const char* __restrict__ qkvB, float* __restrict__ part) {
  __shared__ float obuf[64][64];
  const int p = blockIdx.x & (kClsSplit - 1);
  const int h = (blockIdx.x / kClsSplit) % kH;
  const int b = blockIdx.x / (kClsSplit * kH);
  const int lane = threadIdx.x;
  const int hOff = h * 256;
  const int keysPer = kS / kClsSplit;   // 256

  float q[64];
  {
    const char* qp = qkvB + (size_t)(b * kS) * kRowB + hOff;
#pragma unroll
    for (int g = 0; g < 8; ++g) {
      const u16x8v hv = *(const u16x8v*)(qp + (g << 4));
      const u16x8v lv = *(const u16x8v*)(qp + 128 + (g << 4));
#pragma unroll
      for (int j = 0; j < 8; ++j) q[g * 8 + j] = bf2f(hv[j]) + bf2f(lv[j]);
    }
  }

  float oacc[64] = {};
  float l = 0.f;

  for (int i = 0; i < keysPer / 64; ++i) {
    const int sk = p * keysPer + i * 64 + lane;
    const char* rp = qkvB + (size_t)(b * kS + sk) * kRowB;
    const int swz = sk & 7;
    float dp = 0.f;
#pragma unroll
    for (int g = 0; g < 8; ++g) {
      const char* kp = rp + 3072 + hOff + ((g ^ swz) << 4);
      const u16x8v kh = *(const u16x8v*)kp;
      const u16x8v kl = *(const u16x8v*)(kp + 128);
#pragma unroll
      for (int j = 0; j < 8; ++j)
        dp = fmaf(q[g * 8 + j], bf2f(kh[j]) + bf2f(kl[j]), dp);
    }
    const float e = __expf(dp * kScale);
    l += e;
    const char* vp = rp + 6144 + hOff;
#pragma unroll
    for (int g = 0; g < 8; ++g) {
      const u16x8v vv = *(const u16x8v*)(vp + (g << 4));
#pragma unroll
      for (int j = 0; j < 8; ++j)
        oacc[g * 8 + j] = fmaf(e, bf2f(vv[j]), oacc[g * 8 + j]);
    }
  }

  float L = l;
#pragma unroll
  for (int off = 32; off > 0; off >>= 1) L += __shfl_xor(L, off);

#pragma unroll
  for (int d = 0; d < 64; ++d) obuf[lane][d] = oacc[d];
  __syncthreads();

  float sum = 0.f;
  for (int ln = 0; ln < 64; ++ln) sum += obuf[ln][lane];

  float* dst = part + (size_t)blockIdx.x * 66;
  dst[lane] = sum;
  if (lane == 0) dst[64] = L;
}

// ---------------------------------------------------------------------------
// CLS attention, pass 2: combine partials, normalize, write oh/ol row 0.
// ---------------------------------------------------------------------------
__global__ __launch_bounds__(64)
void attn_cls_comb(const float* __restrict__ part,
                   u16* __restrict__ oh, u16* __restrict__ ol) {
  const int h = blockIdx.x % kH;
  const int b = blockIdx.x / kH;
  const int lane = threadIdx.x;
  const float* src = part + (size_t)((b * kH + h) * kClsSplit) * 66;
  float s = 0.f, L = 0.f;
#pragma unroll
  for (int p = 0; p < kClsSplit; ++p) {
    s += src[p * 66 + lane];
    L += src[p * 66 + 64];
  }
  const float v = s / L;
  const u16 hb = f2bf(v);
  const size_t off0 = (size_t)(b * kS) * kE + h * kD + lane;
  oh[off0] = hb;
  ol[off0] = f2bf(v - bf2f(hb));
}

}  // namespace

// ---------------------------------------------------------------------------
extern "C" void kernel_launch(void* const* d_in, const int* in_sizes, int n_in,
                              void* d_out, int out_size, void* d_ws, size_t ws_size,
                              hipStream_t stream) {
  const float* x      = (const float*)d_in[0];
  const int*   coords = (const int*)d_in[1];
  const float* Wqkv   = (const float*)d_in[2];
  const float* bqkv   = (const float*)d_in[3];
  const float* Wout   = (const float*)d_in[4];
  const float* bout   = (const float*)d_in[5];
  float* out = (float*)d_out;

  // Workspace (100,663,296 B):
  //   A [0 .. 75,497,472)  qkv fp32 -> packed in-slot (q,k hi/lo; v bf16 + V^T)
  //       (aliased post-cls: WoTh @0)
  //   B [75,497,472 .. +25,165,824)  phase1: WqTh @0 (3.5 MB)
  //                                  phase2: oh @0, ol @+12,582,912
  // d_out doubles as scratch (stream-ordered): xh/xl, then cls partials,
  // then the final output overwrites it.
  char* wsb = (char*)d_ws;
  float* qkv  = (float*)wsb;
  char*  qkvB = wsb;
  u16* WoTh = (u16*)wsb;
  char* rb = wsb + 75497472;
  u16* WqTh = (u16*)rb;
  u16* oh   = (u16*)rb;
  u16* ol   = (u16*)(rb + 12582912);
  u16* xh   = (u16*)d_out;
  u16* xl   = (u16*)((char*)d_out + 12582912);
  float* clsPart = out;

  const int M = kB * kS;  // 8192

  // 1. Transpose+bf16 W_qkv (hi only)
  wsplit_t<<<(kQKV / 64) * (kE / 64), 256, 0, stream>>>(Wqkv, WqTh, kE, kQKV);

  // 2. x pre-split (scratch in d_out) + QKV projection (pipelined 2-term GEMM)
  {
    xsplit<<<(M * kE) / (256 * 8), 256, 0, stream>>>(x, xh, xl);
    const int nwg = (kQKV / 128) * (M / 128);   // 1152, %8==0
    gemm_mfma<<<nwg, 256, 0, stream>>>(xh, xl, WqTh, bqkv, qkv, M, kQKV, kE);
  }

  // 3. RoPE + q/k in-slot bf16 pack (coalesced, wave-per-row)
  {
    const int slots = kB * kS * 2;              // 16384
    ropeconv<<<slots / 4, 256, 0, stream>>>(qkvB, coords);
  }

  // 4. V pack
  vtrans<<<kB * kH * (kS / 64), 256, 0, stream>>>(qkvB);

  // 5. Windowed attention (depth-2 pipelined, XCD-swizzled) -> oh/ol
  attn_win_mfma<<<kB * kH * kC * 2, 128, 0, stream>>>(qkvB, oh, ol);

  // 6. CLS attention: 16-way split partials (scratch in d_out) + combine
  attn_cls_part<<<kB * kH * kClsSplit, 64, 0, stream>>>(qkvB, clsPart);
  attn_cls_comb<<<kB * kH, 64, 0, stream>>>(clsPart, oh, ol);

  // 7. Transpose+bf16 W_out (into dead qkv space)
  wsplit_t<<<(kE / 64) * (kE / 64), 256, 0, stream>>>(Wout, WoTh, kE, kE);

  // 8. Output projection (pipelined 2-term, XCD-swizzled)
  {
    const int nwg = (kE / 128) * (M / 128);     // 384, %8==0
    gemm_mfma<<<nwg, 256, 0, stream>>>(oh, ol, WoTh, bout, out, M, kE, kE);
  }
}

// Round 14
// 204.051 us; speedup vs baseline: 1.1717x; 1.1470x over previous
//
#include <hip/hip_runtime.h>

namespace {

typedef unsigned short u16;
typedef __bf16 bf16x8 __attribute__((ext_vector_type(8)));
typedef float f32x4 __attribute__((ext_vector_type(4)));
typedef float f32x16 __attribute__((ext_vector_type(16)));
typedef u16 u16x8v __attribute__((ext_vector_type(8)));
struct alignas(8) u16x4 { u16 x, y, z, w; };
union U32x4 { unsigned int u[4]; bf16x8 v; };

constexpr int kS    = 4096;
constexpr int kE    = 768;
constexpr int kH    = 12;
constexpr int kD    = 64;
constexpr int kQKV  = 2304;   // 3*E
constexpr int kChunk = 256;
constexpr int kC    = 16;     // S / CHUNK
constexpr int kB    = 2;
constexpr float kScale = 0.125f;  // 1/sqrt(64)
constexpr int kRowB = 9216;       // qkv row bytes (2304 fp32-equivalent slots)
constexpr int kClsSplit = 16;     // key-chunks per (b,h) for CLS attention
constexpr float kL2 = 0.83048202372184058696f;  // log2(10000)/16

// ---- bf16 helpers (RNE) ---------------------------------------------------
__device__ __forceinline__ u16 f2bf(float f) {
  unsigned int u = __float_as_uint(f);
  u += 0x7FFFu + ((u >> 16) & 1u);
  return (u16)(u >> 16);
}
__device__ __forceinline__ float bf2f(u16 h) {
  return __uint_as_float(((unsigned int)h) << 16);
}

// ---- XCD-aware bijective block swizzle (grid % 8 == 0) ---------------------
__device__ __forceinline__ int xcd_swz(int bid, int nwg) {
  const int cpx = nwg >> 3;
  return (bid & 7) * cpx + (bid >> 3);
}

// ---- async global->LDS, 16B per lane --------------------------------------
__device__ __forceinline__ void glds16(const void* g, void* l) {
  __builtin_amdgcn_global_load_lds(
      (const __attribute__((address_space(1))) unsigned int*)g,
      (__attribute__((address_space(3))) unsigned int*)l, 16, 0, 0);
}

// ---------------------------------------------------------------------------
// Weight pre-pass: W[K][N] fp32 -> Th[N][K] bf16 (transposed, hi only).
// ---------------------------------------------------------------------------
__global__ __launch_bounds__(256)
void wsplit_t(const float* __restrict__ W, u16* __restrict__ Th, int K, int N) {
  __shared__ float tile[64][65];
  const int ntiles = N >> 6;
  const int n0 = (blockIdx.x % ntiles) << 6;
  const int k0 = (blockIdx.x / ntiles) << 6;
  const int t  = threadIdx.x;
  const int r  = t >> 2;
  const int cs = (t & 3) << 4;
  const float* src = W + (size_t)(k0 + r) * N + n0 + cs;
#pragma unroll
  for (int i = 0; i < 4; ++i) {
    float4 v = *(const float4*)(src + 4 * i);
    tile[r][cs + 4 * i + 0] = v.x;
    tile[r][cs + 4 * i + 1] = v.y;
    tile[r][cs + 4 * i + 2] = v.z;
    tile[r][cs + 4 * i + 3] = v.w;
  }
  __syncthreads();
  u16* dh = Th + (size_t)(n0 + r) * K + k0 + cs;
#pragma unroll
  for (int i = 0; i < 4; ++i) {
    u16x4 hq;
    hq.x = f2bf(tile[cs + 4 * i + 0][r]);
    hq.y = f2bf(tile[cs + 4 * i + 1][r]);
    hq.z = f2bf(tile[cs + 4 * i + 2][r]);
    hq.w = f2bf(tile[cs + 4 * i + 3][r]);
    *(u16x4*)(dh + 4 * i) = hq;
  }
}

// ---------------------------------------------------------------------------
// x pre-split: x fp32 [M][K] -> xh, xl bf16 [M][K]. Scratch = d_out.
// ---------------------------------------------------------------------------
__global__ __launch_bounds__(256)
void xsplit(const float* __restrict__ x, u16* __restrict__ xh, u16* __restrict__ xl) {
  const size_t i8 = ((size_t)blockIdx.x * 256 + threadIdx.x) * 8;
  const float4 v0 = *(const float4*)(x + i8);
  const float4 v1 = *(const float4*)(x + i8 + 4);
  const float f[8] = {v0.x, v0.y, v0.z, v0.w, v1.x, v1.y, v1.z, v1.w};
  u16x8v hv, lv;
#pragma unroll
  for (int j = 0; j < 8; ++j) {
    const u16 hb = f2bf(f[j]);
    hv[j] = hb;
    lv[j] = f2bf(f[j] - bf2f(hb));
  }
  *(u16x8v*)(xh + i8) = hv;
  *(u16x8v*)(xl + i8) = lv;
}

// ---------------------------------------------------------------------------
// Split-bf16 MFMA GEMM, 2-term, depth-2 pipelined (round-11 loop).
// QKV=false: plain fp32 C + bias epilogue (out-projection).
// QKV=true : fused epilogue — RoPE + bf16 hi/lo pack for q/k slots,
//            bf16 lower + swizzled V^T upper for v slots. Writes the packed
//            qkv layout directly; no fp32 qkv buffer, no rope/vtrans passes.
// ---------------------------------------------------------------------------
template <bool QKV>
__global__ __launch_bounds__(256, 2)
void gemm_mfma(const u16* __restrict__ Ahg, const u16* __restrict__ Alg,
               const u16* __restrict__ Bhg,
               const float* __restrict__ bias, float* __restrict__ C,
               char* __restrict__ outPk, const int* __restrict__ coords,
               int M, int N, int K) {
  // flat LDS: [AsH 2x128x32 | AsL | BsH] = 24576 u16 = 48 KB.
  // After the K-loop the whole buffer is dead -> epilogue V^T bounce aliases it.
  __shared__ __align__(16) u16 smem[24576];
  u16* AsH = smem;
  u16* AsL = smem + 8192;
  u16* BsH = smem + 16384;

  const int nwg = gridDim.x;
  const int lid = xcd_swz(blockIdx.x, nwg);
  const int nTiles = N >> 7;
  const int m0 = (lid / nTiles) << 7;
  const int n0 = (lid % nTiles) << 7;

  const int tid  = threadIdx.x;
  const int wave = tid >> 6;
  const int lane = tid & 63;
  const int l15  = lane & 15;
  const int khf  = lane >> 4;
  const int wm   = wave >> 1;
  const int wn   = wave & 1;

  const int c0 = wave * 2, c1 = wave * 2 + 1;
  const int rr = lane >> 2;
  const int gg = lane & 3;

  const size_t bOff0 = (size_t)(n0 + c0 * 16 + rr) * K + gg * 8;
  const size_t bOff1 = (size_t)(n0 + c1 * 16 + rr) * K + gg * 8;
  const size_t aOff0 = (size_t)(m0 + c0 * 16 + rr) * K + gg * 8;
  const size_t aOff1 = (size_t)(m0 + c1 * 16 + rr) * K + gg * 8;

  auto STAGE = [&](int p, int k0) {
    glds16(Bhg + bOff0 + k0, BsH + p * 4096 + (c0 * 16) * 32);
    glds16(Bhg + bOff1 + k0, BsH + p * 4096 + (c1 * 16) * 32);
    glds16(Ahg + aOff0 + k0, AsH + p * 4096 + (c0 * 16) * 32);
    glds16(Ahg + aOff1 + k0, AsH + p * 4096 + (c1 * 16) * 32);
    glds16(Alg + aOff0 + k0, AsL + p * 4096 + (c0 * 16) * 32);
    glds16(Alg + aOff1 + k0, AsL + p * 4096 + (c1 * 16) * 32);
  };

  f32x4 acc[4][4];
#pragma unroll
  for (int i = 0; i < 4; ++i)
#pragma unroll
    for (int j = 0; j < 4; ++j) acc[i][j] = (f32x4){0.f, 0.f, 0.f, 0.f};

  auto COMPUTE = [&](int p) {
    bf16x8 fah[4], fal[4], fbh[4];
#pragma unroll
    for (int f = 0; f < 4; ++f) {
      fah[f] = *(const bf16x8*)&AsH[p * 4096 + (wm * 64 + f * 16 + l15) * 32 + khf * 8];
      fal[f] = *(const bf16x8*)&AsL[p * 4096 + (wm * 64 + f * 16 + l15) * 32 + khf * 8];
      fbh[f] = *(const bf16x8*)&BsH[p * 4096 + (wn * 64 + f * 16 + l15) * 32 + khf * 8];
    }
#pragma unroll
    for (int mi = 0; mi < 4; ++mi)
#pragma unroll
      for (int ni = 0; ni < 4; ++ni)
        acc[mi][ni] = __builtin_amdgcn_mfma_f32_16x16x32_bf16(fah[mi], fbh[ni], acc[mi][ni], 0, 0, 0);
#pragma unroll
    for (int mi = 0; mi < 4; ++mi)
#pragma unroll
      for (int ni = 0; ni < 4; ++ni)
        acc[mi][ni] = __builtin_amdgcn_mfma_f32_16x16x32_bf16(fal[mi], fbh[ni], acc[mi][ni], 0, 0, 0);
  };

  STAGE(0, 0);
  STAGE(1, 32);
  int cur = 0;

  for (int k0 = 0; k0 < K - 32; k0 += 32) {
    asm volatile("s_waitcnt vmcnt(6)" ::: "memory");
    __builtin_amdgcn_sched_barrier(0);
    __builtin_amdgcn_s_barrier();

    COMPUTE(cur);

    __builtin_amdgcn_sched_barrier(0);
    asm volatile("s_waitcnt lgkmcnt(0)" ::: "memory");
    __builtin_amdgcn_s_barrier();
    if (k0 + 64 < K) STAGE(cur, k0 + 64);
    cur ^= 1;
  }

  asm volatile("s_waitcnt vmcnt(0)" ::: "memory");
  __builtin_amdgcn_sched_barrier(0);
  __builtin_amdgcn_s_barrier();
  COMPUTE(cur);

  if constexpr (!QKV) {
#pragma unroll
    for (int ni = 0; ni < 4; ++ni) {
      const int col = n0 + wn * 64 + ni * 16 + l15;
      const float bv = bias[col];
#pragma unroll
      for (int mi = 0; mi < 4; ++mi) {
        const int rbase = m0 + wm * 64 + mi * 16 + khf * 4;
#pragma unroll
        for (int r = 0; r < 4; ++r)
          C[(size_t)(rbase + r) * N + col] = acc[mi][ni][r] + bv;
      }
    }
  } else {
    __syncthreads();   // all LDS staging reads done; smem free for bounce

    const int col64  = (n0 >> 6) + wn;   // 0..35
    const int sector = col64 / 12;       // 0=q, 1=k, 2=v
    const int hh     = col64 % 12;
    const int rowbase = m0 + wm * 64;    // 64-aligned

    if (sector < 2) {
      // ---- q/k: RoPE (pair partner in adjacent lane) + hi/lo pack ----
      const int sel = sector;
#pragma unroll
      for (int mi = 0; mi < 4; ++mi)
#pragma unroll
        for (int r = 0; r < 4; ++r) {
          const int row = rowbase + mi * 16 + khf * 4 + r;
          const int bb = row >> 12;
          const int ss = row & 4095;
          float cx = 0.f, cy = 0.f;
          if (ss >= 1) {
            const size_t ci = ((size_t)bb * (kS - 1) + (ss - 1)) * 2;
            cx = (float)coords[ci]     * (1.0f / 100000.0f);
            cy = (float)coords[ci + 1] * (1.0f / 100000.0f);
          }
          const int swz = (sel == 1) ? (ss & 7) : 0;
          char* base = outPk + (size_t)row * kRowB + sel * 3072 + hh * 256;
#pragma unroll
          for (int ni = 0; ni < 4; ++ni) {
            const int d = ni * 16 + l15;
            const float v0 = acc[mi][ni][r] + bias[n0 + wn * 64 + ni * 16 + l15];
            const float pv = __shfl_xor(v0, 1);   // partner d^1 (all lanes exec)
            float nv = v0;
            if (ss >= 1) {
              const float coord = (d < 32) ? cx : cy;
              const float ang = coord * exp2f(-(float)((d >> 1) & 15) * kL2);
              const float sn = __sinf(ang), cn = __cosf(ang);
              nv = (d & 1) ? fmaf(v0, cn, pv * sn) : fmaf(v0, cn, -pv * sn);
            }
            const u16 hb = f2bf(nv);
            const u16 lb = f2bf(nv - bf2f(hb));
            const int gofs = (((d >> 3) ^ swz) << 4) + (d & 7) * 2;
            *(u16*)(base + gofs) = hb;
            *(u16*)(base + 128 + gofs) = lb;
          }
        }
    } else {
      // ---- v: lower row-major bf16 + upper swizzled V^T via LDS bounce ----
      u16* ldsT = smem + wave * 4352;    // 64 x 68 u16 per wave (8.5 KB)
#pragma unroll
      for (int mi = 0; mi < 4; ++mi)
#pragma unroll
        for (int ni = 0; ni < 4; ++ni)
#pragma unroll
          for (int r = 0; r < 4; ++r) {
            const int key = mi * 16 + khf * 4 + r;   // row within 64-group
            const int row = rowbase + key;
            const int d = ni * 16 + l15;
            const float v0 = acc[mi][ni][r] + bias[n0 + wn * 64 + ni * 16 + l15];
            const u16 hb = f2bf(v0);
            *(u16*)(outPk + (size_t)row * kRowB + 6144 + hh * 256 + d * 2) = hb;
            ldsT[d * 68 + key] = hb;
          }
      // compiler inserts lgkmcnt before dependent reads (same-wave LDS)
      const int dd = lane;               // V^T row = d
      char* vbase = outPk + (size_t)(rowbase + dd) * kRowB + 6144 + hh * 256 + 128;
#pragma unroll
      for (int kg = 0; kg < 8; ++kg) {
        const u16x4 a0 = *(const u16x4*)&ldsT[dd * 68 + kg * 8];
        const u16x4 a1 = *(const u16x4*)&ldsT[dd * 68 + kg * 8 + 4];
        char* dst = vbase + ((kg ^ (dd & 7)) << 4);
        *(u16x4*)dst = a0;
        *(u16x4*)(dst + 8) = a1;
      }
    }
  }
}

// ---------------------------------------------------------------------------
// Windowed attention (round-11 version, measured 76 us): 32x32x16 MFMA,
// 2-wave blocks, XCD swizzle, glds staging, in-register P redistribution.
// ---------------------------------------------------------------------------
__global__ __launch_bounds__(128)
void attn_win_mfma(const char* __restrict__ qkvB,
                   u16* __restrict__ oh, u16* __restrict__ ol) {
  __shared__ __align__(16) u16 KsH[4096];
  __shared__ __align__(16) u16 KsL[4096];
  __shared__ __align__(16) u16 VsT[4096];
  __shared__ float ls[2][64];

  const int idx  = xcd_swz(blockIdx.x, gridDim.x);
  const int half = idx & 1;
  const int c = (idx >> 1) % kC;
  const int h = ((idx >> 1) / kC) % kH;
  const int b = idx / (2 * kC * kH);
  const int tid  = threadIdx.x;
  const int w    = tid >> 6;           // 0..1
  const int lane = tid & 63;
  const int l31  = lane & 31;
  const int h5   = lane >> 5;
  const int hOff = h * 256;
  const int qbase = c * kChunk + half * 128 + w * 64;

  bf16x8 Qh[2][4], Ql[2][4];
#pragma unroll
  for (int ti = 0; ti < 2; ++ti) {
    const size_t grow = (size_t)(b * kS + qbase + ti * 32 + l31);
#pragma unroll
    for (int ksl = 0; ksl < 4; ++ksl) {
      const char* p = qkvB + grow * kRowB + hOff + ((ksl * 2 + h5) << 4);
      Qh[ti][ksl] = *(const bf16x8*)p;
      Ql[ti][ksl] = *(const bf16x8*)(p + 128);
    }
  }

  f32x16 Oacc[2][2];
#pragma unroll
  for (int a = 0; a < 2; ++a)
#pragma unroll
    for (int d = 0; d < 2; ++d)
#pragma unroll
      for (int i = 0; i < 16; ++i) Oacc[a][d][i] = 0.f;
  float lsA[2] = {0.f, 0.f};

  const int clo = (c > 0) ? c - 1 : 0;
  const int chi = (c < kC - 1) ? c + 1 : kC - 1;
  const int nwin = (chi - clo + 1) * 4;
  const int ntiles = nwin + ((clo != 0) ? 1 : 0);

  U32x4 pa[2][4];

  for (int tt = 0; tt < ntiles; ++tt) {
    const bool isCls = (tt >= nwin);
    const int srow = isCls ? 0 : (clo * kChunk + tt * 64);

    __syncthreads();
#pragma unroll
    for (int j = 0; j < 4; ++j) {
      const int cb = w * 256 + j * 64;     // wave-uniform LDS chunk base
      const int ch = cb + lane;
      const size_t gr = (size_t)(b * kS + srow + (ch >> 3)) * kRowB + ((ch & 7) << 4);
      glds16(qkvB + gr + 3072 + hOff,       &KsH[cb * 8]);
      glds16(qkvB + gr + 3072 + hOff + 128, &KsL[cb * 8]);
      glds16(qkvB + gr + 6144 + hOff + 128, &VsT[cb * 8]);
    }
    __syncthreads();

#pragma unroll
    for (int kt = 0; kt < 2; ++kt) {
      bf16x8 KH[4], KL[4];
      const int krow = kt * 32 + l31;
#pragma unroll
      for (int ksl = 0; ksl < 4; ++ksl) {
        const int gg = (((ksl * 2 + h5) ^ (krow & 7)) << 3);
        KH[ksl] = *(const bf16x8*)&KsH[krow * 64 + gg];
        KL[ksl] = *(const bf16x8*)&KsL[krow * 64 + gg];
      }
#pragma unroll
      for (int ti = 0; ti < 2; ++ti) {
        f32x16 S;
#pragma unroll
        for (int i = 0; i < 16; ++i) S[i] = 0.f;
#pragma unroll
        for (int ksl = 0; ksl < 4; ++ksl) {
          S = __builtin_amdgcn_mfma_f32_32x32x16_bf16(KH[ksl], Qh[ti][ksl], S, 0, 0, 0);
          S = __builtin_amdgcn_mfma_f32_32x32x16_bf16(KH[ksl], Ql[ti][ksl], S, 0, 0, 0);
          S = __builtin_amdgcn_mfma_f32_32x32x16_bf16(KL[ksl], Qh[ti][ksl], S, 0, 0, 0);
        }
        unsigned int wpk[4][2], sw[4][2];
        float lacc = 0.f;
#pragma unroll
        for (int m = 0; m < 4; ++m) {
          float e[4];
#pragma unroll
          for (int r = 0; r < 4; ++r) {
            float ev = __expf(S[4 * m + r] * kScale);
            if (isCls && !(kt == 0 && m == 0 && r == 0 && h5 == 0)) ev = 0.f;
            e[r] = ev;
          }
          lacc += (e[0] + e[1]) + (e[2] + e[3]);
          wpk[m][0] = (unsigned int)f2bf(e[0]) | ((unsigned int)f2bf(e[1]) << 16);
          wpk[m][1] = (unsigned int)f2bf(e[2]) | ((unsigned int)f2bf(e[3]) << 16);
        }
        lsA[ti] += lacc;
#pragma unroll
        for (int m = 0; m < 4; ++m) {
          sw[m][0] = __shfl_xor(wpk[m][0], 32);
          sw[m][1] = __shfl_xor(wpk[m][1], 32);
        }
#pragma unroll
        for (int jj = 0; jj < 2; ++jj) {
          const int m0 = 2 * jj, m1 = 2 * jj + 1;
          U32x4& P = pa[ti][kt * 2 + jj];
          P.u[0] = h5 ? sw[m1][0]  : wpk[m0][0];
          P.u[1] = h5 ? sw[m1][1]  : wpk[m0][1];
          P.u[2] = h5 ? wpk[m1][0] : sw[m0][0];
          P.u[3] = h5 ? wpk[m1][1] : sw[m0][1];
        }
      }
    }

#pragma unroll
    for (int sl = 0; sl < 4; ++sl) {
#pragma unroll
      for (int dt = 0; dt < 2; ++dt) {
        const int vrow = dt * 32 + l31;
        const bf16x8 vb =
            *(const bf16x8*)&VsT[vrow * 64 + ((((sl * 2 + h5) ^ (vrow & 7))) << 3)];
        Oacc[0][dt] = __builtin_amdgcn_mfma_f32_32x32x16_bf16(pa[0][sl].v, vb, Oacc[0][dt], 0, 0, 0);
        Oacc[1][dt] = __builtin_amdgcn_mfma_f32_32x32x16_bf16(pa[1][sl].v, vb, Oacc[1][dt], 0, 0, 0);
      }
    }
  }

#pragma unroll
  for (int ti = 0; ti < 2; ++ti) {
    float v = lsA[ti];
    v += __shfl_xor(v, 32);
    ls[w][ti * 32 + l31] = v;
  }

#pragma unroll
  for (int ti = 0; ti < 2; ++ti)
#pragma unroll
    for (int m = 0; m < 4; ++m)
#pragma unroll
      for (int r = 0; r < 4; ++r) {
        const int qr = r + 8 * m + 4 * h5;
        const float inv = 1.0f / ls[w][ti * 32 + qr];
        const size_t grow = (size_t)(b * kS + qbase + ti * 32 + qr);
#pragma unroll
        for (int dt = 0; dt < 2; ++dt) {
          const float val = Oacc[ti][dt][4 * m + r] * inv;
          const u16 hb = f2bf(val);
          const size_t o = grow * (size_t)kE + h * 64 + dt * 32 + l31;
          oh[o] = hb;
          ol[o] = f2bf(val - bf2f(hb));
        }
      }
}

// ---------------------------------------------------------------------------
// CLS attention, pass 1: partials over 256-key chunks (16-way split).
// ---------------------------------------------------------------------------
__global__ __launch_bounds__(64)
void attn_cls_part(const char* __restrict__ qkvB, float* __restrict__ part) {
  __shared__ float obuf[64][64];
  const int p = blockIdx.x & (kClsSplit - 1);
  const int h = (blockIdx.x / kClsSplit) % kH;
  const int b = blockIdx.x / (kClsSplit * kH);
  const int lane = threadIdx.x;
  const int hOff = h * 256;
  const int keysPer = kS / kClsSplit;   // 256

  float q[64];
  {
    const char* qp = qkvB + (size_t)(b * kS) * kRowB + hOff;
#pragma unroll
    for (int g = 0; g < 8; ++g) {
      const u16x8v hv = *(const u16x8v*)(qp + (g << 4));
      const u16x8v lv = *(const u16x8v*)(qp + 128 + (g << 4));
#pragma unroll
      for (int j = 0; j < 8; ++j) q[g * 8 + j] = bf2f(hv[j]) + bf2f(lv[j]);
    }
  }

  float oacc[64] = {};
  float l = 0.f;

  for (int i = 0; i < keysPer / 64; ++i) {
    const int sk = p * keysPer + i * 64 + lane;
    const char* rp = qkvB + (size_t)(b * kS + sk) * kRowB;
    const int swz = sk & 7;
    float dp = 0.f;
#pragma unroll
    for (int g = 0; g < 8; ++g) {
      const char* kp = rp + 3072 + hOff + ((g ^ swz) << 4);
      const u16x8v kh = *(const u16x8v*)kp;
      const u16x8v kl = *(const u16x8v*)(kp + 128);
#pragma unroll
      for (int j = 0; j < 8; ++j)
        dp = fmaf(q[g * 8 + j], bf2f(kh[j]) + bf2f(kl[j]), dp);
    }
    const float e = __expf(dp * kScale);
    l += e;
    const char* vp = rp + 6144 + hOff;
#pragma unroll
    for (int g = 0; g < 8; ++g) {
      const u16x8v vv = *(const u16x8v*)(vp + (g << 4));
#pragma unroll
      for (int j = 0; j < 8; ++j)
        oacc[g * 8 + j] = fmaf(e, bf2f(vv[j]), oacc[g * 8 + j]);
    }
  }

  float L = l;
#pragma unroll
  for (int off = 32; off > 0; off >>= 1) L += __shfl_xor(L, off);

#pragma unroll
  for (int d = 0; d < 64; ++d) obuf[lane][d] = oacc[d];
  __syncthreads();

  float sum = 0.f;
  for (int ln = 0; ln < 64; ++ln) sum += obuf[ln][lane];

  float* dst = part + (size_t)blockIdx.x * 66;
  dst[lane] = sum;
  if (lane == 0) dst[64] = L;
}

// ---------------------------------------------------------------------------
// CLS attention, pass 2: combine partials, normalize, write oh/ol row 0.
// ---------------------------------------------------------------------------
__global__ __launch_bounds__(64)
void attn_cls_comb(const float* __restrict__ part,
                   u16* __restrict__ oh, u16* __restrict__ ol) {
  const int h = blockIdx.x % kH;
  const int b = blockIdx.x / kH;
  const int lane = threadIdx.x;
  const float* src = part + (size_t)((b * kH + h) * kClsSplit) * 66;
  float s = 0.f, L = 0.f;
#pragma unroll
  for (int p = 0; p < kClsSplit; ++p) {
    s += src[p * 66 + lane];
    L += src[p * 66 + 64];
  }
  const float v = s / L;
  const u16 hb = f2bf(v);
  const size_t off0 = (size_t)(b * kS) * kE + h * kD + lane;
  oh[off0] = hb;
  ol[off0] = f2bf(v - bf2f(hb));
}

}  // namespace

// ---------------------------------------------------------------------------
extern "C" void kernel_launch(void* const* d_in, const int* in_sizes, int n_in,
                              void* d_out, int out_size, void* d_ws, size_t ws_size,
                              hipStream_t stream) {
  const float* x      = (const float*)d_in[0];
  const int*   coords = (const int*)d_in[1];
  const float* Wqkv   = (const float*)d_in[2];
  const float* bqkv   = (const float*)d_in[3];
  const float* Wout   = (const float*)d_in[4];
  const float* bout   = (const float*)d_in[5];
  float* out = (float*)d_out;

  // Workspace (100,663,296 B):
  //   A [0 .. 75,497,472)  packed qkv [B*S][9216B]: q,k = hi|lo bf16 (k group-
  //       swizzled), v = lower bf16 | upper V^T swizzled. Written DIRECTLY by
  //       the fused QKV GEMM epilogue. (aliased post-cls: WoTh @0)
  //   B [75,497,472 .. +25,165,824)  phase1: WqTh @0 (3.5 MB)
  //                                  phase2: oh @0, ol @+12,582,912
  // d_out doubles as scratch (stream-ordered): xh/xl, then cls partials,
  // then the final output overwrites it.
  char* wsb = (char*)d_ws;
  char*  qkvB = wsb;
  u16* WoTh = (u16*)wsb;
  char* rb = wsb + 75497472;
  u16* WqTh = (u16*)rb;
  u16* oh   = (u16*)rb;
  u16* ol   = (u16*)(rb + 12582912);
  u16* xh   = (u16*)d_out;
  u16* xl   = (u16*)((char*)d_out + 12582912);
  float* clsPart = out;

  const int M = kB * kS;  // 8192

  // 1. Transpose+bf16 W_qkv (hi only)
  wsplit_t<<<(kQKV / 64) * (kE / 64), 256, 0, stream>>>(Wqkv, WqTh, kE, kQKV);

  // 2. x pre-split (scratch in d_out) + QKV projection with FUSED
  //    rope/pack/V^T epilogue -> packed qkvB (no separate rope/vtrans passes)
  {
    xsplit<<<(M * kE) / (256 * 8), 256, 0, stream>>>(x, xh, xl);
    const int nwg = (kQKV / 128) * (M / 128);   // 1152, %8==0
    gemm_mfma<true><<<nwg, 256, 0, stream>>>(xh, xl, WqTh, bqkv, nullptr,
                                             qkvB, coords, M, kQKV, kE);
  }

  // 3. Windowed attention (round-11 structure, XCD-swizzled) -> oh/ol
  attn_win_mfma<<<kB * kH * kC * 2, 128, 0, stream>>>(qkvB, oh, ol);

  // 4. CLS attention: 16-way split partials (scratch in d_out) + combine
  attn_cls_part<<<kB * kH * kClsSplit, 64, 0, stream>>>(qkvB, clsPart);
  attn_cls_comb<<<kB * kH, 64, 0, stream>>>(clsPart, oh, ol);

  // 5. Transpose+bf16 W_out (into dead qkv space)
  wsplit_t<<<(kE / 64) * (kE / 64), 256, 0, stream>>>(Wout, WoTh, kE, kE);

  // 6. Output projection (plain epilogue, XCD-swizzled)
  {
    const int nwg = (kE / 128) * (M / 128);     // 384, %8==0
    gemm_mfma<false><<<nwg, 256, 0, stream>>>(oh, ol, WoTh, bout, out,
                                              nullptr, nullptr, M, kE, kE);
  }
}